// Round 1
// baseline (2629.342 us; speedup 1.0000x reference)
//
#include <hip/hip_runtime.h>
#include <hip/hip_bf16.h>

// Problem constants (B=1)
#define SEQ   2048
#define HID   2048
#define NH    16
#define NKV   2
#define DH    128
#define SCALE 0.08838834764831845f   // 1/sqrt(128)

// ---------------------------------------------------------------------------
// Generic fp32 GEMM: C[M,N] = A[M,K] @ W[K,N] (+ bias). 128x128 tile, BK=8,
// 256 threads, 8x8 per-thread register tile. M,N multiples of 128, K of 8.
// ---------------------------------------------------------------------------
__global__ __launch_bounds__(256) void gemm128(const float* __restrict__ A,
                                               const float* __restrict__ W,
                                               const float* __restrict__ bias,
                                               float* __restrict__ C,
                                               int M, int N, int K)
{
    __shared__ float As[8][132];   // transposed A tile, +4 pad keeps 16B align & kills conflicts
    __shared__ float Ws[8][132];

    const int tid  = threadIdx.x;
    const int brow = blockIdx.y * 128;
    const int bcol = blockIdx.x * 128;
    const int tr   = (tid >> 4) * 8;   // 0..120
    const int tc   = (tid & 15) * 8;

    const int ar = tid >> 1;           // A tile row 0..127
    const int ac = (tid & 1) * 4;      // A tile col group {0,4}
    const int wr = tid >> 5;           // W tile row 0..7
    const int wc = (tid & 31) * 4;     // W tile col group 0..124

    float acc[8][8];
#pragma unroll
    for (int i = 0; i < 8; ++i)
#pragma unroll
        for (int j = 0; j < 8; ++j) acc[i][j] = 0.f;

    for (int k0 = 0; k0 < K; k0 += 8) {
        float4 a4 = *(const float4*)(A + (size_t)(brow + ar) * K + k0 + ac);
        float4 w4 = *(const float4*)(W + (size_t)(k0 + wr) * N + bcol + wc);
        __syncthreads();
        As[ac + 0][ar] = a4.x;
        As[ac + 1][ar] = a4.y;
        As[ac + 2][ar] = a4.z;
        As[ac + 3][ar] = a4.w;
        *(float4*)&Ws[wr][wc] = w4;
        __syncthreads();
#pragma unroll
        for (int kk = 0; kk < 8; ++kk) {
            float av[8], wv[8];
            *(float4*)&av[0] = *(const float4*)&As[kk][tr];
            *(float4*)&av[4] = *(const float4*)&As[kk][tr + 4];
            *(float4*)&wv[0] = *(const float4*)&Ws[kk][tc];
            *(float4*)&wv[4] = *(const float4*)&Ws[kk][tc + 4];
#pragma unroll
            for (int i = 0; i < 8; ++i)
#pragma unroll
                for (int j = 0; j < 8; ++j) acc[i][j] += av[i] * wv[j];
        }
    }

#pragma unroll
    for (int i = 0; i < 8; ++i) {
        float* crow = C + (size_t)(brow + tr + i) * N + bcol + tc;
#pragma unroll
        for (int j4 = 0; j4 < 2; ++j4) {
            float4 cv;
            float b0 = bias ? bias[bcol + tc + j4 * 4 + 0] : 0.f;
            float b1 = bias ? bias[bcol + tc + j4 * 4 + 1] : 0.f;
            float b2 = bias ? bias[bcol + tc + j4 * 4 + 2] : 0.f;
            float b3 = bias ? bias[bcol + tc + j4 * 4 + 3] : 0.f;
            cv.x = acc[i][j4 * 4 + 0] + b0;
            cv.y = acc[i][j4 * 4 + 1] + b1;
            cv.z = acc[i][j4 * 4 + 2] + b2;
            cv.w = acc[i][j4 * 4 + 3] + b3;
            *(float4*)(crow + j4 * 4) = cv;
        }
    }
}

// ---------------------------------------------------------------------------
// In-place RoPE on a (SEQ, nh*128) projection. One thread per (s, h, d<64).
// out[d]    = x[d]*cos[s,d]      - x[d+64]*sin[s,d]
// out[d+64] = x[d+64]*cos[s,d+64] + x[d]  *sin[s,d+64]
// ---------------------------------------------------------------------------
__global__ void rope_kernel(float* __restrict__ x,
                            const float* __restrict__ cosp,
                            const float* __restrict__ sinp, int nh)
{
    int idx = blockIdx.x * blockDim.x + threadIdx.x;
    int d = idx & 63;
    int h = (idx >> 6) % nh;
    int s = idx / (64 * nh);
    if (s >= SEQ) return;
    float* base = x + (size_t)s * (nh * DH) + h * DH;
    float x0 = base[d], x1 = base[d + 64];
    float c0 = cosp[s * DH + d],  c1 = cosp[s * DH + d + 64];
    float s0 = sinp[s * DH + d],  s1 = sinp[s * DH + d + 64];
    base[d]      = x0 * c0 - x1 * s0;
    base[d + 64] = x1 * c1 + x0 * s1;
}

// ---------------------------------------------------------------------------
// Flash-style causal attention with online softmax, fp32.
// Grid: (SEQ/64 q-blocks, NH heads). Block: 256 threads.
// Thread t: q-row qr = t>>2, column-quarter cpart = t&3 (8 scores / 32 O elems).
// ---------------------------------------------------------------------------
__global__ __launch_bounds__(256) void attn_kernel(const float* __restrict__ Qp,
                                                   const float* __restrict__ Kp,
                                                   const float* __restrict__ Vp,
                                                   float* __restrict__ ctx)
{
    const int qb   = blockIdx.x;     // 0..31
    const int h    = blockIdx.y;     // 0..15
    const int kvh  = h >> 3;         // GQA: N_REP = 8
    const int tid  = threadIdx.x;
    const int lane = tid & 63;

    __shared__ float Qs[64][132];    // +4 pad: conflict-free float4 reads
    __shared__ float Ks[32][132];
    __shared__ float Vs[32][132];

    // Load Q tile (64 x 128): 32 floats (8 float4) per thread
    {
        int r  = tid >> 2;
        int c0 = (tid & 3) * 32;
        const float4* src = (const float4*)(Qp + (size_t)(qb * 64 + r) * (NH * DH) + h * DH + c0);
        float4* dst = (float4*)&Qs[r][c0];
#pragma unroll
        for (int i = 0; i < 8; ++i) dst[i] = src[i];
    }

    const int qr    = tid >> 2;
    const int qg    = qb * 64 + qr;
    const int cpart = tid & 3;

    float m_old = -1e30f, l = 0.f;
    float o[32];
#pragma unroll
    for (int i = 0; i < 32; ++i) o[i] = 0.f;

    const int nkt = qb * 2 + 2;      // k-tiles of 32 rows, causal bound
    for (int kt = 0; kt < nkt; ++kt) {
        __syncthreads();             // previous iteration done reading Ks/Vs (also fences Qs store)
        {
            int r  = tid >> 3;       // 0..31
            int c0 = (tid & 7) * 16;
            const float4* ks = (const float4*)(Kp + (size_t)(kt * 32 + r) * (NKV * DH) + kvh * DH + c0);
            const float4* vs = (const float4*)(Vp + (size_t)(kt * 32 + r) * (NKV * DH) + kvh * DH + c0);
            float4* kd = (float4*)&Ks[r][c0];
            float4* vd = (float4*)&Vs[r][c0];
#pragma unroll
            for (int i = 0; i < 4; ++i) kd[i] = ks[i];
#pragma unroll
            for (int i = 0; i < 4; ++i) vd[i] = vs[i];
        }
        __syncthreads();

        // ---- scores: 8 per thread ----
        float sc[8];
#pragma unroll
        for (int j = 0; j < 8; ++j) sc[j] = 0.f;
#pragma unroll
        for (int d4 = 0; d4 < 32; ++d4) {
            float4 q4 = ((const float4*)&Qs[qr][0])[d4];
#pragma unroll
            for (int j = 0; j < 8; ++j) {
                float4 k4 = ((const float4*)&Ks[cpart * 8 + j][0])[d4];
                sc[j] += q4.x * k4.x + q4.y * k4.y + q4.z * k4.z + q4.w * k4.w;
            }
        }
#pragma unroll
        for (int j = 0; j < 8; ++j) {
            int kg = kt * 32 + cpart * 8 + j;
            sc[j] = (kg <= qg) ? sc[j] * SCALE : -1e30f;
        }

        // ---- online softmax (row = 4 lanes: xor 1,2) ----
        float mt = sc[0];
#pragma unroll
        for (int j = 1; j < 8; ++j) mt = fmaxf(mt, sc[j]);
        mt = fmaxf(mt, __shfl_xor(mt, 1, 64));
        mt = fmaxf(mt, __shfl_xor(mt, 2, 64));
        float m_new = fmaxf(m_old, mt);
        float alpha = __expf(m_old - m_new);
        float p[8], ps = 0.f;
#pragma unroll
        for (int j = 0; j < 8; ++j) { p[j] = __expf(sc[j] - m_new); ps += p[j]; }
        ps += __shfl_xor(ps, 1, 64);
        ps += __shfl_xor(ps, 2, 64);
        l = l * alpha + ps;
        m_old = m_new;
#pragma unroll
        for (int i = 0; i < 32; ++i) o[i] *= alpha;

        // ---- PV accumulate: O[qr][cpart*32..+32] += P[qr][kc] * V[kc][...] ----
#pragma unroll
        for (int kc = 0; kc < 32; ++kc) {
            int owner = (lane & ~3) + (kc >> 3);
            float pk = __shfl(p[kc & 7], owner, 64);
            const float4* vrow = (const float4*)&Vs[kc][cpart * 32];
#pragma unroll
            for (int d4 = 0; d4 < 8; ++d4) {
                float4 v4 = vrow[d4];
                o[d4 * 4 + 0] += pk * v4.x;
                o[d4 * 4 + 1] += pk * v4.y;
                o[d4 * 4 + 2] += pk * v4.z;
                o[d4 * 4 + 3] += pk * v4.w;
            }
        }
    }

    float inv = 1.f / l;
    float* dst = ctx + (size_t)qg * (NH * DH) + h * DH + cpart * 32;
#pragma unroll
    for (int d4 = 0; d4 < 8; ++d4) {
        float4 w;
        w.x = o[d4 * 4 + 0] * inv;
        w.y = o[d4 * 4 + 1] * inv;
        w.z = o[d4 * 4 + 2] * inv;
        w.w = o[d4 * 4 + 3] * inv;
        ((float4*)dst)[d4] = w;
    }
}

// ---------------------------------------------------------------------------
extern "C" void kernel_launch(void* const* d_in, const int* in_sizes, int n_in,
                              void* d_out, int out_size, void* d_ws, size_t ws_size,
                              hipStream_t stream)
{
    const float* hs   = (const float*)d_in[0];
    const float* cosp = (const float*)d_in[1];
    const float* sinp = (const float*)d_in[2];
    // d_in[3] attention_mask: pure causal, handled analytically
    const float* Wq = (const float*)d_in[4];
    const float* bq = (const float*)d_in[5];
    const float* Wk = (const float*)d_in[6];
    const float* bk = (const float*)d_in[7];
    const float* Wv = (const float*)d_in[8];
    const float* bv = (const float*)d_in[9];
    const float* Wo = (const float*)d_in[10];
    float* out = (float*)d_out;

    float* ws     = (float*)d_ws;
    float* q_proj = ws;                                   // SEQ x 2048
    float* k_proj = q_proj + (size_t)SEQ * (NH * DH);     // SEQ x 256
    float* v_proj = k_proj + (size_t)SEQ * (NKV * DH);    // SEQ x 256
    float* ctx    = v_proj + (size_t)SEQ * (NKV * DH);    // SEQ x 2048

    dim3 blk(256);
    gemm128<<<dim3(NH * DH / 128, SEQ / 128), blk, 0, stream>>>(hs, Wq, bq, q_proj, SEQ, NH * DH, HID);
    gemm128<<<dim3(NKV * DH / 128, SEQ / 128), blk, 0, stream>>>(hs, Wk, bk, k_proj, SEQ, NKV * DH, HID);
    gemm128<<<dim3(NKV * DH / 128, SEQ / 128), blk, 0, stream>>>(hs, Wv, bv, v_proj, SEQ, NKV * DH, HID);

    rope_kernel<<<(SEQ * NH * 64) / 256, 256, 0, stream>>>(q_proj, cosp, sinp, NH);
    rope_kernel<<<(SEQ * NKV * 64) / 256, 256, 0, stream>>>(k_proj, cosp, sinp, NKV);

    attn_kernel<<<dim3(SEQ / 64, NH), blk, 0, stream>>>(q_proj, k_proj, v_proj, ctx);

    gemm128<<<dim3(HID / 128, SEQ / 128), blk, 0, stream>>>(ctx, Wo, nullptr, out, SEQ, HID, HID);
}

// Round 3
// 1518.579 us; speedup vs baseline: 1.7314x; 1.7314x over previous
//
#include <hip/hip_runtime.h>
#include <hip/hip_bf16.h>

// Problem constants (B=1)
#define SEQ   2048
#define HID   2048
#define NH    16
#define NKV   2
#define DH    128
#define SCALE 0.08838834764831845f   // 1/sqrt(128)
#define LOG2E 1.4426950408889634f

typedef short bf16x8 __attribute__((ext_vector_type(8)));
typedef float f32x4  __attribute__((ext_vector_type(4)));

__device__ __forceinline__ short f2bf(float x) {
    unsigned u = __float_as_uint(x);
    u += 0x7FFF + ((u >> 16) & 1);          // round-to-nearest-even
    return (short)(u >> 16);
}

// ---------------------------------------------------------------------------
// fp32 GEMM: C[M,N] = A[M,K] @ W[K,N] (+ bias). 128x128 tile, BK=8.
// ---------------------------------------------------------------------------
__global__ __launch_bounds__(256) void gemm128(const float* __restrict__ A,
                                               const float* __restrict__ W,
                                               const float* __restrict__ bias,
                                               float* __restrict__ C,
                                               int M, int N, int K)
{
    __shared__ float As[8][132];
    __shared__ float Ws[8][132];

    const int tid  = threadIdx.x;
    const int brow = blockIdx.y * 128;
    const int bcol = blockIdx.x * 128;
    const int tr   = (tid >> 4) * 8;
    const int tc   = (tid & 15) * 8;

    const int ar = tid >> 1;
    const int ac = (tid & 1) * 4;
    const int wr = tid >> 5;
    const int wc = (tid & 31) * 4;

    float acc[8][8];
#pragma unroll
    for (int i = 0; i < 8; ++i)
#pragma unroll
        for (int j = 0; j < 8; ++j) acc[i][j] = 0.f;

    for (int k0 = 0; k0 < K; k0 += 8) {
        float4 a4 = *(const float4*)(A + (size_t)(brow + ar) * K + k0 + ac);
        float4 w4 = *(const float4*)(W + (size_t)(k0 + wr) * N + bcol + wc);
        __syncthreads();
        As[ac + 0][ar] = a4.x;
        As[ac + 1][ar] = a4.y;
        As[ac + 2][ar] = a4.z;
        As[ac + 3][ar] = a4.w;
        *(float4*)&Ws[wr][wc] = w4;
        __syncthreads();
#pragma unroll
        for (int kk = 0; kk < 8; ++kk) {
            float av[8], wv[8];
            *(float4*)&av[0] = *(const float4*)&As[kk][tr];
            *(float4*)&av[4] = *(const float4*)&As[kk][tr + 4];
            *(float4*)&wv[0] = *(const float4*)&Ws[kk][tc];
            *(float4*)&wv[4] = *(const float4*)&Ws[kk][tc + 4];
#pragma unroll
            for (int i = 0; i < 8; ++i)
#pragma unroll
                for (int j = 0; j < 8; ++j) acc[i][j] += av[i] * wv[j];
        }
    }

#pragma unroll
    for (int i = 0; i < 8; ++i) {
        float* crow = C + (size_t)(brow + tr + i) * N + bcol + tc;
#pragma unroll
        for (int j4 = 0; j4 < 2; ++j4) {
            float4 cv;
            float b0 = bias ? bias[bcol + tc + j4 * 4 + 0] : 0.f;
            float b1 = bias ? bias[bcol + tc + j4 * 4 + 1] : 0.f;
            float b2 = bias ? bias[bcol + tc + j4 * 4 + 2] : 0.f;
            float b3 = bias ? bias[bcol + tc + j4 * 4 + 3] : 0.f;
            cv.x = acc[i][j4 * 4 + 0] + b0;
            cv.y = acc[i][j4 * 4 + 1] + b1;
            cv.z = acc[i][j4 * 4 + 2] + b2;
            cv.w = acc[i][j4 * 4 + 3] + b3;
            *(float4*)(crow + j4 * 4) = cv;
        }
    }
}

// ---------------------------------------------------------------------------
// RoPE in-place on fp32 Q projection.
// ---------------------------------------------------------------------------
__global__ void rope_kernel(float* __restrict__ x,
                            const float* __restrict__ cosp,
                            const float* __restrict__ sinp, int nh)
{
    int idx = blockIdx.x * blockDim.x + threadIdx.x;
    int d = idx & 63;
    int h = (idx >> 6) % nh;
    int s = idx / (64 * nh);
    if (s >= SEQ) return;
    float* base = x + (size_t)s * (nh * DH) + h * DH;
    float x0 = base[d], x1 = base[d + 64];
    float c0 = cosp[s * DH + d],  c1 = cosp[s * DH + d + 64];
    float s0 = sinp[s * DH + d],  s1 = sinp[s * DH + d + 64];
    base[d]      = x0 * c0 - x1 * s0;
    base[d + 64] = x1 * c1 + x0 * s1;
}

// ---------------------------------------------------------------------------
// RoPE K (fp32 in) -> bf16 out, row-major [s][kvh*128+d].
// ---------------------------------------------------------------------------
__global__ void ropebf_k(const float* __restrict__ kp,
                         const float* __restrict__ cosp,
                         const float* __restrict__ sinp,
                         short* __restrict__ kb)
{
    int idx = blockIdx.x * blockDim.x + threadIdx.x;   // SEQ*NKV*64
    int d   = idx & 63;
    int kvh = (idx >> 6) & (NKV - 1);
    int s   = idx >> 7;
    if (s >= SEQ) return;
    const float* base = kp + (size_t)s * (NKV * DH) + kvh * DH;
    float x0 = base[d], x1 = base[d + 64];
    float c0 = cosp[s * DH + d],  c1 = cosp[s * DH + d + 64];
    float s0 = sinp[s * DH + d],  s1 = sinp[s * DH + d + 64];
    short* ob = kb + (size_t)s * (NKV * DH) + kvh * DH;
    ob[d]      = f2bf(x0 * c0 - x1 * s0);
    ob[d + 64] = f2bf(x1 * c1 + x0 * s1);
}

// ---------------------------------------------------------------------------
// V fp32 [s][kvh*128+d] -> bf16 transposed vt[kvh][d][s]
// ---------------------------------------------------------------------------
__global__ void vt_conv(const float* __restrict__ vp, short* __restrict__ vt)
{
    int idx = blockIdx.x * blockDim.x + threadIdx.x;   // NKV*128*SEQ
    int s   = idx & (SEQ - 1);
    int d   = (idx >> 11) & (DH - 1);
    int kvh = idx >> 18;
    vt[idx] = f2bf(vp[(size_t)s * (NKV * DH) + kvh * DH + d]);
}

// ---------------------------------------------------------------------------
// MFMA flash attention, bf16 inputs / fp32 softmax+accum.
// Grid: 512 blocks (qb remapped for balance, 16 heads). Block: 256 = 4 waves.
// Wave w owns 16 q-rows; K/V^T tiles (32 cols) staged in LDS, shared by waves.
// ---------------------------------------------------------------------------
__global__ __launch_bounds__(256) void attn_mfma(const float* __restrict__ Qp,
                                                 const short* __restrict__ Kb,
                                                 const short* __restrict__ Vtb,
                                                 float* __restrict__ ctx)
{
    __shared__ short Ks[32][136];      // stride 272B: 16B-aligned, 2-way banks
    __shared__ short Vs[128][40];      // V^T tile, stride 80B
    __shared__ short Ps[4][16][40];    // per-wave P round-trip

    const int bid = blockIdx.x;
    const int h   = bid & 15;
    const int j   = bid >> 4;
    const int qb  = (j < 16) ? j : 47 - j;   // pair heavy with light blocks
    const int kvh = h >> 3;
    const int tid  = threadIdx.x;
    const int wave = tid >> 6;
    const int lane = tid & 63;
    const int quad = lane >> 4;
    const int l16  = lane & 15;

    const int qrow0 = qb * 64 + wave * 16;

    // Q fragments in A-layout (m=l16 -> q-row, k=quad*8+j -> d), bf16
    bf16x8 aq[4];
    {
        const float* qsrc = Qp + (size_t)(qrow0 + l16) * HID + h * DH + quad * 8;
#pragma unroll
        for (int c = 0; c < 4; ++c) {
            float4 f0 = *(const float4*)(qsrc + c * 32);
            float4 f1 = *(const float4*)(qsrc + c * 32 + 4);
            bf16x8 a;
            a[0] = f2bf(f0.x); a[1] = f2bf(f0.y); a[2] = f2bf(f0.z); a[3] = f2bf(f0.w);
            a[4] = f2bf(f1.x); a[5] = f2bf(f1.y); a[6] = f2bf(f1.z); a[7] = f2bf(f1.w);
            aq[c] = a;
        }
    }

    f32x4 of[8];
#pragma unroll
    for (int t = 0; t < 8; ++t) of[t] = (f32x4){0.f, 0.f, 0.f, 0.f};
    float m_old[4] = {-1e30f, -1e30f, -1e30f, -1e30f};
    float l_sum[4] = {0.f, 0.f, 0.f, 0.f};

    const int nkt = (qb + 1) * 2;
    const float SL = SCALE * LOG2E;

    for (int kt = 0; kt < nkt; ++kt) {
        const int kbase = kt * 32;
        __syncthreads();                               // prev iter done reading
        {   // stage K tile: 32 rows x 128 bf16 = 512 int4 chunks, 2 per thread
#pragma unroll
            for (int i = 0; i < 2; ++i) {
                int cid = tid + i * 256;
                int r = cid >> 4, c = (cid & 15) * 8;
                *(int4*)&Ks[r][c] =
                    *(const int4*)(Kb + (size_t)(kbase + r) * (NKV * DH) + kvh * DH + c);
            }
        }
        {   // stage V^T tile: 128 rows x 32 bf16 = 512 int4 chunks, 2 per thread
#pragma unroll
            for (int i = 0; i < 2; ++i) {
                int cid = tid + i * 256;
                int d = cid >> 2, c = (cid & 3) * 8;
                *(int4*)&Vs[d][c] =
                    *(const int4*)(Vtb + (size_t)kvh * DH * SEQ + (size_t)d * SEQ + kbase + c);
            }
        }
        __syncthreads();

        // ---- QK^T: two 16-col tiles, D=128 in 4 chunks ----
        f32x4 s0 = (f32x4){0.f, 0.f, 0.f, 0.f};
        f32x4 s1 = (f32x4){0.f, 0.f, 0.f, 0.f};
#pragma unroll
        for (int c = 0; c < 4; ++c) {
            bf16x8 bk0 = *(const bf16x8*)&Ks[l16][c * 32 + quad * 8];
            bf16x8 bk1 = *(const bf16x8*)&Ks[16 + l16][c * 32 + quad * 8];
            s0 = __builtin_amdgcn_mfma_f32_16x16x32_bf16(aq[c], bk0, s0, 0, 0, 0);
            s1 = __builtin_amdgcn_mfma_f32_16x16x32_bf16(aq[c], bk1, s1, 0, 0, 0);
        }

        // ---- online softmax (log2 domain), C-layout rows quad*4+r ----
        float alpha[4];
#pragma unroll
        for (int r = 0; r < 4; ++r) {
            int qg = qrow0 + quad * 4 + r;
            bool v0 = (kbase + l16)      <= qg;
            bool v1 = (kbase + 16 + l16) <= qg;
            float x0 = v0 ? s0[r] * SL : -1e30f;
            float x1 = v1 ? s1[r] * SL : -1e30f;
            float mr = fmaxf(x0, x1);
            mr = fmaxf(mr, __shfl_xor(mr, 1));
            mr = fmaxf(mr, __shfl_xor(mr, 2));
            mr = fmaxf(mr, __shfl_xor(mr, 4));
            mr = fmaxf(mr, __shfl_xor(mr, 8));
            float mn = fmaxf(m_old[r], mr);
            alpha[r] = __builtin_amdgcn_exp2f(m_old[r] - mn);
            float p0 = v0 ? __builtin_amdgcn_exp2f(x0 - mn) : 0.f;
            float p1 = v1 ? __builtin_amdgcn_exp2f(x1 - mn) : 0.f;
            float ps = p0 + p1;
            ps += __shfl_xor(ps, 1);
            ps += __shfl_xor(ps, 2);
            ps += __shfl_xor(ps, 4);
            ps += __shfl_xor(ps, 8);
            l_sum[r] = l_sum[r] * alpha[r] + ps;
            m_old[r] = mn;
            Ps[wave][quad * 4 + r][l16]      = f2bf(p0);
            Ps[wave][quad * 4 + r][16 + l16] = f2bf(p1);
        }
#pragma unroll
        for (int t = 0; t < 8; ++t)
#pragma unroll
            for (int r = 0; r < 4; ++r) of[t][r] *= alpha[r];

        __syncthreads();   // P C-layout -> A-layout round trip (uniform: all waves)

        // ---- PV: O[16x128] += P[16x32] @ V[32x128] ----
        bf16x8 ap = *(const bf16x8*)&Ps[wave][l16][quad * 8];
#pragma unroll
        for (int t = 0; t < 8; ++t) {
            bf16x8 bv = *(const bf16x8*)&Vs[t * 16 + l16][quad * 8];
            of[t] = __builtin_amdgcn_mfma_f32_16x16x32_bf16(ap, bv, of[t], 0, 0, 0);
        }
    }

    // epilogue: normalize, store (C-layout: row=quad*4+r, col=t*16+l16)
#pragma unroll
    for (int r = 0; r < 4; ++r) {
        float inv = 1.f / l_sum[r];
        float* dst = ctx + (size_t)(qrow0 + quad * 4 + r) * HID + h * DH + l16;
#pragma unroll
        for (int t = 0; t < 8; ++t) dst[t * 16] = of[t][r] * inv;
    }
}

// ---------------------------------------------------------------------------
extern "C" void kernel_launch(void* const* d_in, const int* in_sizes, int n_in,
                              void* d_out, int out_size, void* d_ws, size_t ws_size,
                              hipStream_t stream)
{
    const float* hs   = (const float*)d_in[0];
    const float* cosp = (const float*)d_in[1];
    const float* sinp = (const float*)d_in[2];
    const float* Wq = (const float*)d_in[4];
    const float* bq = (const float*)d_in[5];
    const float* Wk = (const float*)d_in[6];
    const float* bk = (const float*)d_in[7];
    const float* Wv = (const float*)d_in[8];
    const float* bv = (const float*)d_in[9];
    const float* Wo = (const float*)d_in[10];
    float* out = (float*)d_out;

    float* q_proj = (float*)d_ws;                              // 2048x2048 f32
    float* k_proj = q_proj + (size_t)SEQ * HID;                // 2048x256 f32
    float* v_proj = k_proj + (size_t)SEQ * (NKV * DH);         // 2048x256 f32
    float* ctx    = v_proj + (size_t)SEQ * (NKV * DH);         // 2048x2048 f32
    short* kbf    = (short*)(ctx + (size_t)SEQ * HID);         // 2048x256 bf16
    short* vtb    = kbf + (size_t)SEQ * (NKV * DH);            // 2x128x2048 bf16

    dim3 blk(256);
    gemm128<<<dim3(NH * DH / 128, SEQ / 128), blk, 0, stream>>>(hs, Wq, bq, q_proj, SEQ, NH * DH, HID);
    gemm128<<<dim3(NKV * DH / 128, SEQ / 128), blk, 0, stream>>>(hs, Wk, bk, k_proj, SEQ, NKV * DH, HID);
    gemm128<<<dim3(NKV * DH / 128, SEQ / 128), blk, 0, stream>>>(hs, Wv, bv, v_proj, SEQ, NKV * DH, HID);

    rope_kernel<<<(SEQ * NH * 64) / 256, 256, 0, stream>>>(q_proj, cosp, sinp, NH);
    ropebf_k<<<(SEQ * NKV * 64) / 256, 256, 0, stream>>>(k_proj, cosp, sinp, kbf);
    vt_conv<<<(NKV * DH * SEQ) / 256, 256, 0, stream>>>(v_proj, vtb);

    attn_mfma<<<dim3(32 * NH), blk, 0, stream>>>(q_proj, kbf, vtb, ctx);

    gemm128<<<dim3(HID / 128, SEQ / 128), blk, 0, stream>>>(ctx, Wo, nullptr, out, SEQ, HID, HID);
}

// Round 4
// 351.754 us; speedup vs baseline: 7.4750x; 4.3172x over previous
//
#include <hip/hip_runtime.h>
#include <hip/hip_bf16.h>

// Problem constants (B=1)
#define SEQ   2048
#define HID   2048
#define NH    16
#define NKV   2
#define DH    128
#define QKVN  2560                       // 2048 (Q) + 256 (K) + 256 (V)
#define SCALE 0.08838834764831845f      // 1/sqrt(128)
#define LOG2E 1.4426950408889634f

typedef short bf16x8 __attribute__((ext_vector_type(8)));
typedef short bf16x4 __attribute__((ext_vector_type(4)));
typedef float f32x4  __attribute__((ext_vector_type(4)));

__device__ __forceinline__ short f2bf(float x) {
    unsigned u = __float_as_uint(x);
    u += 0x7FFF + ((u >> 16) & 1);          // round-to-nearest-even
    return (short)(u >> 16);
}

__device__ __forceinline__ void gl2lds16(const short* g, short* l) {
    __builtin_amdgcn_global_load_lds(
        (const __attribute__((address_space(1))) int*)g,
        (__attribute__((address_space(3))) int*)l, 16, 0, 0);
}

// ---------------------------------------------------------------------------
// fp32 -> bf16 elementwise (4 elems/thread)
// ---------------------------------------------------------------------------
__global__ void cvt_bf16(const float* __restrict__ s, short* __restrict__ d)
{
    int i = blockIdx.x * 256 + threadIdx.x;
    float4 v = ((const float4*)s)[i];
    bf16x4 o = { f2bf(v.x), f2bf(v.y), f2bf(v.z), f2bf(v.w) };
    ((bf16x4*)d)[i] = o;
}

// ---------------------------------------------------------------------------
// fp32 [K][N] -> bf16 [N][K] transpose+convert. Block (32,8), tile 32x32.
// ---------------------------------------------------------------------------
__global__ void transp_bf(const float* __restrict__ src, short* __restrict__ dst,
                          int N, int K)
{
    __shared__ short t[32][33];
    int bx = blockIdx.x * 32;      // n tile
    int by = blockIdx.y * 32;      // k tile
    int lx = threadIdx.x, ly = threadIdx.y;
#pragma unroll
    for (int i = 0; i < 4; ++i)
        t[ly + i * 8][lx] = f2bf(src[(size_t)(by + ly + i * 8) * N + bx + lx]);
    __syncthreads();
#pragma unroll
    for (int i = 0; i < 4; ++i)
        dst[(size_t)(bx + ly + i * 8) * K + by + lx] = t[lx][ly + i * 8];
}

// ---------------------------------------------------------------------------
// bf16 MFMA GEMM (m97 structure): C[M,N] = A[M,K] @ Bt[N,K]^T (+bias).
// 128x128 tile, BK=32, 4 waves x (4x4 of 16x16x32), global_load_lds staging.
// ---------------------------------------------------------------------------
__global__ __launch_bounds__(256) void gemm_bt(const short* __restrict__ A,
                                               const short* __restrict__ Bt,
                                               const float* __restrict__ bias,
                                               float* __restrict__ C,
                                               int M, int N, int K)
{
    __shared__ short As[128 * 32];     // row-major [128][32], no padding
    __shared__ short Bs[128 * 32];

    const int tid  = threadIdx.x;
    const int wave = tid >> 6;
    const int lane = tid & 63;
    const int quad = lane >> 4;
    const int l16  = lane & 15;
    const int m0 = blockIdx.y * 128;
    const int n0 = blockIdx.x * 128;
    const int wm = (wave >> 1) * 64;
    const int wn = (wave & 1) * 64;

    // staging: slot s = j*256+tid <-> row=s>>2, colgroup=s&3  (identity map)
    const int r0 = tid >> 2;
    const int c0 = (tid & 3) * 8;
    const short* gA = A  + (size_t)(m0 + r0) * K + c0;
    const short* gB = Bt + (size_t)(n0 + r0) * K + c0;
    short* lA = As + wave * 512;       // (wave*64 slots)*8 shorts
    short* lB = Bs + wave * 512;

    f32x4 acc[4][4];
#pragma unroll
    for (int i = 0; i < 4; ++i)
#pragma unroll
        for (int j = 0; j < 4; ++j) acc[i][j] = (f32x4){0.f, 0.f, 0.f, 0.f};

    for (int k0 = 0; k0 < K; k0 += 32) {
        __syncthreads();
        gl2lds16(gA + k0,                lA);
        gl2lds16(gA + k0 + (size_t)64 * K, lA + 2048);
        gl2lds16(gB + k0,                lB);
        gl2lds16(gB + k0 + (size_t)64 * K, lB + 2048);
        __syncthreads();

        bf16x8 av[4], bv[4];
#pragma unroll
        for (int mt = 0; mt < 4; ++mt)
            av[mt] = *(const bf16x8*)&As[(wm + mt * 16 + l16) * 32 + quad * 8];
#pragma unroll
        for (int nt = 0; nt < 4; ++nt)
            bv[nt] = *(const bf16x8*)&Bs[(wn + nt * 16 + l16) * 32 + quad * 8];
#pragma unroll
        for (int mt = 0; mt < 4; ++mt)
#pragma unroll
            for (int nt = 0; nt < 4; ++nt)
                acc[mt][nt] = __builtin_amdgcn_mfma_f32_16x16x32_bf16(
                    av[mt], bv[nt], acc[mt][nt], 0, 0, 0);
    }

#pragma unroll
    for (int mt = 0; mt < 4; ++mt)
#pragma unroll
        for (int nt = 0; nt < 4; ++nt) {
            int col = n0 + wn + nt * 16 + l16;
            float b = bias ? bias[col] : 0.f;
#pragma unroll
            for (int r = 0; r < 4; ++r) {
                int row = m0 + wm + mt * 16 + quad * 4 + r;
                C[(size_t)row * N + col] = acc[mt][nt][r] + b;
            }
        }
}

// ---------------------------------------------------------------------------
// RoPE in-place on fp32 Q columns of qkv (row stride QKVN).
// ---------------------------------------------------------------------------
__global__ void rope_kernel(float* __restrict__ x,
                            const float* __restrict__ cosp,
                            const float* __restrict__ sinp)
{
    int idx = blockIdx.x * blockDim.x + threadIdx.x;   // SEQ*NH*64
    int d = idx & 63;
    int h = (idx >> 6) & (NH - 1);
    int s = idx >> 10;
    if (s >= SEQ) return;
    float* base = x + (size_t)s * QKVN + h * DH;
    float x0 = base[d], x1 = base[d + 64];
    float c0 = cosp[s * DH + d],  c1 = cosp[s * DH + d + 64];
    float s0 = sinp[s * DH + d],  s1 = sinp[s * DH + d + 64];
    base[d]      = x0 * c0 - x1 * s0;
    base[d + 64] = x1 * c1 + x0 * s1;
}

// ---------------------------------------------------------------------------
// RoPE K (fp32, row stride QKVN) -> bf16 row-major [s][kvh*128+d].
// ---------------------------------------------------------------------------
__global__ void ropebf_k(const float* __restrict__ kp,
                         const float* __restrict__ cosp,
                         const float* __restrict__ sinp,
                         short* __restrict__ kb)
{
    int idx = blockIdx.x * blockDim.x + threadIdx.x;   // SEQ*NKV*64
    int d   = idx & 63;
    int kvh = (idx >> 6) & (NKV - 1);
    int s   = idx >> 7;
    if (s >= SEQ) return;
    const float* base = kp + (size_t)s * QKVN + kvh * DH;
    float x0 = base[d], x1 = base[d + 64];
    float c0 = cosp[s * DH + d],  c1 = cosp[s * DH + d + 64];
    float s0 = sinp[s * DH + d],  s1 = sinp[s * DH + d + 64];
    short* ob = kb + (size_t)s * (NKV * DH) + kvh * DH;
    ob[d]      = f2bf(x0 * c0 - x1 * s0);
    ob[d + 64] = f2bf(x1 * c1 + x0 * s1);
}

// ---------------------------------------------------------------------------
// V (fp32, row stride QKVN) -> bf16 transposed vt[kvh][d][s]
// ---------------------------------------------------------------------------
__global__ void vt_conv(const float* __restrict__ vp, short* __restrict__ vt)
{
    int idx = blockIdx.x * blockDim.x + threadIdx.x;   // NKV*128*SEQ
    int s   = idx & (SEQ - 1);
    int d   = (idx >> 11) & (DH - 1);
    int kvh = idx >> 18;
    vt[idx] = f2bf(vp[(size_t)s * QKVN + kvh * DH + d]);
}

// ---------------------------------------------------------------------------
// MFMA flash attention, bf16 inputs / fp32 softmax+accum. ctx out is bf16.
// ---------------------------------------------------------------------------
__global__ __launch_bounds__(256) void attn_mfma(const float* __restrict__ Qp,
                                                 const short* __restrict__ Kb,
                                                 const short* __restrict__ Vtb,
                                                 short* __restrict__ ctx)
{
    __shared__ short Ks[32][136];
    __shared__ short Vs[128][40];
    __shared__ short Ps[4][16][40];

    const int bid = blockIdx.x;
    const int h   = bid & 15;
    const int j   = bid >> 4;
    const int qb  = (j < 16) ? j : 47 - j;
    const int kvh = h >> 3;
    const int tid  = threadIdx.x;
    const int wave = tid >> 6;
    const int lane = tid & 63;
    const int quad = lane >> 4;
    const int l16  = lane & 15;

    const int qrow0 = qb * 64 + wave * 16;

    bf16x8 aq[4];
    {
        const float* qsrc = Qp + (size_t)(qrow0 + l16) * QKVN + h * DH + quad * 8;
#pragma unroll
        for (int c = 0; c < 4; ++c) {
            float4 f0 = *(const float4*)(qsrc + c * 32);
            float4 f1 = *(const float4*)(qsrc + c * 32 + 4);
            bf16x8 a;
            a[0] = f2bf(f0.x); a[1] = f2bf(f0.y); a[2] = f2bf(f0.z); a[3] = f2bf(f0.w);
            a[4] = f2bf(f1.x); a[5] = f2bf(f1.y); a[6] = f2bf(f1.z); a[7] = f2bf(f1.w);
            aq[c] = a;
        }
    }

    f32x4 of[8];
#pragma unroll
    for (int t = 0; t < 8; ++t) of[t] = (f32x4){0.f, 0.f, 0.f, 0.f};
    float m_old[4] = {-1e30f, -1e30f, -1e30f, -1e30f};
    float l_sum[4] = {0.f, 0.f, 0.f, 0.f};

    const int nkt = (qb + 1) * 2;
    const float SL = SCALE * LOG2E;

    for (int kt = 0; kt < nkt; ++kt) {
        const int kbase = kt * 32;
        __syncthreads();
        {
#pragma unroll
            for (int i = 0; i < 2; ++i) {
                int cid = tid + i * 256;
                int r = cid >> 4, c = (cid & 15) * 8;
                *(int4*)&Ks[r][c] =
                    *(const int4*)(Kb + (size_t)(kbase + r) * (NKV * DH) + kvh * DH + c);
            }
        }
        {
#pragma unroll
            for (int i = 0; i < 2; ++i) {
                int cid = tid + i * 256;
                int d = cid >> 2, c = (cid & 3) * 8;
                *(int4*)&Vs[d][c] =
                    *(const int4*)(Vtb + (size_t)kvh * DH * SEQ + (size_t)d * SEQ + kbase + c);
            }
        }
        __syncthreads();

        f32x4 s0 = (f32x4){0.f, 0.f, 0.f, 0.f};
        f32x4 s1 = (f32x4){0.f, 0.f, 0.f, 0.f};
#pragma unroll
        for (int c = 0; c < 4; ++c) {
            bf16x8 bk0 = *(const bf16x8*)&Ks[l16][c * 32 + quad * 8];
            bf16x8 bk1 = *(const bf16x8*)&Ks[16 + l16][c * 32 + quad * 8];
            s0 = __builtin_amdgcn_mfma_f32_16x16x32_bf16(aq[c], bk0, s0, 0, 0, 0);
            s1 = __builtin_amdgcn_mfma_f32_16x16x32_bf16(aq[c], bk1, s1, 0, 0, 0);
        }

        float alpha[4];
#pragma unroll
        for (int r = 0; r < 4; ++r) {
            int qg = qrow0 + quad * 4 + r;
            bool v0 = (kbase + l16)      <= qg;
            bool v1 = (kbase + 16 + l16) <= qg;
            float x0 = v0 ? s0[r] * SL : -1e30f;
            float x1 = v1 ? s1[r] * SL : -1e30f;
            float mr = fmaxf(x0, x1);
            mr = fmaxf(mr, __shfl_xor(mr, 1));
            mr = fmaxf(mr, __shfl_xor(mr, 2));
            mr = fmaxf(mr, __shfl_xor(mr, 4));
            mr = fmaxf(mr, __shfl_xor(mr, 8));
            float mn = fmaxf(m_old[r], mr);
            alpha[r] = __builtin_amdgcn_exp2f(m_old[r] - mn);
            float p0 = v0 ? __builtin_amdgcn_exp2f(x0 - mn) : 0.f;
            float p1 = v1 ? __builtin_amdgcn_exp2f(x1 - mn) : 0.f;
            float ps = p0 + p1;
            ps += __shfl_xor(ps, 1);
            ps += __shfl_xor(ps, 2);
            ps += __shfl_xor(ps, 4);
            ps += __shfl_xor(ps, 8);
            l_sum[r] = l_sum[r] * alpha[r] + ps;
            m_old[r] = mn;
            Ps[wave][quad * 4 + r][l16]      = f2bf(p0);
            Ps[wave][quad * 4 + r][16 + l16] = f2bf(p1);
        }
#pragma unroll
        for (int t = 0; t < 8; ++t)
#pragma unroll
            for (int r = 0; r < 4; ++r) of[t][r] *= alpha[r];

        __syncthreads();

        bf16x8 ap = *(const bf16x8*)&Ps[wave][l16][quad * 8];
#pragma unroll
        for (int t = 0; t < 8; ++t) {
            bf16x8 bv = *(const bf16x8*)&Vs[t * 16 + l16][quad * 8];
            of[t] = __builtin_amdgcn_mfma_f32_16x16x32_bf16(ap, bv, of[t], 0, 0, 0);
        }
    }

#pragma unroll
    for (int r = 0; r < 4; ++r) {
        float inv = 1.f / l_sum[r];
        short* dst = ctx + (size_t)(qrow0 + quad * 4 + r) * HID + h * DH + l16;
#pragma unroll
        for (int t = 0; t < 8; ++t) dst[t * 16] = f2bf(of[t][r] * inv);
    }
}

// ---------------------------------------------------------------------------
extern "C" void kernel_launch(void* const* d_in, const int* in_sizes, int n_in,
                              void* d_out, int out_size, void* d_ws, size_t ws_size,
                              hipStream_t stream)
{
    const float* hs   = (const float*)d_in[0];
    const float* cosp = (const float*)d_in[1];
    const float* sinp = (const float*)d_in[2];
    const float* Wq = (const float*)d_in[4];
    const float* bq = (const float*)d_in[5];
    const float* Wk = (const float*)d_in[6];
    const float* bk = (const float*)d_in[7];
    const float* Wv = (const float*)d_in[8];
    const float* bv = (const float*)d_in[9];
    const float* Wo = (const float*)d_in[10];
    float* out = (float*)d_out;

    char* w = (char*)d_ws;
    short* hsb    = (short*)w;  w += (size_t)SEQ * HID * 2;           // 8 MB
    short* btq    = (short*)w;  w += (size_t)QKVN * HID * 2;          // 10 MB
    short* wot    = (short*)w;  w += (size_t)HID * HID * 2;           // 8 MB
    float* biaskv = (float*)w;  w += QKVN * 4;
    float* qkv    = (float*)w;  w += (size_t)SEQ * QKVN * 4;          // 20 MB
    short* kbf    = (short*)w;  w += (size_t)SEQ * (NKV * DH) * 2;    // 1 MB
    short* vtb    = (short*)w;  w += (size_t)NKV * DH * SEQ * 2;      // 1 MB
    short* ctxb   = (short*)w;                                        // 8 MB

    // 1. convert hidden states to bf16
    cvt_bf16<<<(SEQ * HID) / 1024, 256, 0, stream>>>(hs, hsb);

    // 2. transpose+convert weights to bf16 [N][K]
    transp_bf<<<dim3(HID / 32, HID / 32), dim3(32, 8), 0, stream>>>(Wq, btq, HID, HID);
    transp_bf<<<dim3((NKV * DH) / 32, HID / 32), dim3(32, 8), 0, stream>>>(Wk, btq + (size_t)2048 * HID, NKV * DH, HID);
    transp_bf<<<dim3((NKV * DH) / 32, HID / 32), dim3(32, 8), 0, stream>>>(Wv, btq + (size_t)2304 * HID, NKV * DH, HID);
    transp_bf<<<dim3(HID / 32, HID / 32), dim3(32, 8), 0, stream>>>(Wo, wot, HID, HID);

    // 3. concat biases
    hipMemcpyAsync(biaskv,        bq, 2048 * 4, hipMemcpyDeviceToDevice, stream);
    hipMemcpyAsync(biaskv + 2048, bk,  256 * 4, hipMemcpyDeviceToDevice, stream);
    hipMemcpyAsync(biaskv + 2304, bv,  256 * 4, hipMemcpyDeviceToDevice, stream);

    // 4. fused QKV projection: [2048,2048] @ [2048,2560] -> [2048,2560]
    gemm_bt<<<dim3(QKVN / 128, SEQ / 128), 256, 0, stream>>>(hsb, btq, biaskv, qkv, SEQ, QKVN, HID);

    // 5. RoPE + layout converts
    rope_kernel<<<(SEQ * NH * 64) / 256, 256, 0, stream>>>(qkv, cosp, sinp);
    ropebf_k<<<(SEQ * NKV * 64) / 256, 256, 0, stream>>>(qkv + NH * DH, cosp, sinp, kbf);
    vt_conv<<<(NKV * DH * SEQ) / 256, 256, 0, stream>>>(qkv + NH * DH + NKV * DH, vtb);

    // 6. attention (ctx out in bf16)
    attn_mfma<<<dim3(32 * NH), 256, 0, stream>>>(qkv, kbf, vtb, ctxb);

    // 7. output projection
    gemm_bt<<<dim3(HID / 128, SEQ / 128), 256, 0, stream>>>(ctxb, wot, nullptr, out, SEQ, HID, HID);
}

// Round 5
// 329.092 us; speedup vs baseline: 7.9897x; 1.0689x over previous
//
#include <hip/hip_runtime.h>
#include <hip/hip_bf16.h>

// Problem constants (B=1)
#define SEQ   2048
#define HID   2048
#define NH    16
#define NKV   2
#define DH    128
#define QKVN  2560                       // 2048 (Q) + 256 (K) + 256 (V)
#define SCALE 0.08838834764831845f      // 1/sqrt(128)
#define LOG2E 1.4426950408889634f

typedef short bf16x8 __attribute__((ext_vector_type(8)));
typedef short bf16x4 __attribute__((ext_vector_type(4)));
typedef float f32x4  __attribute__((ext_vector_type(4)));

__device__ __forceinline__ short f2bf(float x) {
    unsigned u = __float_as_uint(x);
    u += 0x7FFF + ((u >> 16) & 1);          // round-to-nearest-even
    return (short)(u >> 16);
}

__device__ __forceinline__ void gl2lds16(const short* g, short* l) {
    __builtin_amdgcn_global_load_lds(
        (const __attribute__((address_space(1))) int*)g,
        (__attribute__((address_space(3))) int*)l, 16, 0, 0);
}

// ---------------------------------------------------------------------------
// fp32 -> bf16 elementwise (4 elems/thread)
// ---------------------------------------------------------------------------
__global__ void cvt_bf16(const float* __restrict__ s, short* __restrict__ d)
{
    int i = blockIdx.x * 256 + threadIdx.x;
    float4 v = ((const float4*)s)[i];
    bf16x4 o = { f2bf(v.x), f2bf(v.y), f2bf(v.z), f2bf(v.w) };
    ((bf16x4*)d)[i] = o;
}

// ---------------------------------------------------------------------------
// fp32 [K][N] -> bf16 [N][K] transpose+convert. Block (32,8), tile 32x32.
// ---------------------------------------------------------------------------
__global__ void transp_bf(const float* __restrict__ src, short* __restrict__ dst,
                          int N, int K)
{
    __shared__ short t[32][33];
    int bx = blockIdx.x * 32;      // n tile
    int by = blockIdx.y * 32;      // k tile
    int lx = threadIdx.x, ly = threadIdx.y;
#pragma unroll
    for (int i = 0; i < 4; ++i)
        t[ly + i * 8][lx] = f2bf(src[(size_t)(by + ly + i * 8) * N + bx + lx]);
    __syncthreads();
#pragma unroll
    for (int i = 0; i < 4; ++i)
        dst[(size_t)(bx + ly + i * 8) * K + by + lx] = t[lx][ly + i * 8];
}

// ---------------------------------------------------------------------------
// bf16 MFMA GEMM (m97 structure): C[M,N] = A[M,K] @ Bt[N,K]^T (+bias).
// ---------------------------------------------------------------------------
__global__ __launch_bounds__(256) void gemm_bt(const short* __restrict__ A,
                                               const short* __restrict__ Bt,
                                               const float* __restrict__ bias,
                                               float* __restrict__ C,
                                               int M, int N, int K)
{
    __shared__ short As[128 * 32];     // row-major [128][32], no padding
    __shared__ short Bs[128 * 32];

    const int tid  = threadIdx.x;
    const int wave = tid >> 6;
    const int lane = tid & 63;
    const int quad = lane >> 4;
    const int l16  = lane & 15;
    const int m0 = blockIdx.y * 128;
    const int n0 = blockIdx.x * 128;
    const int wm = (wave >> 1) * 64;
    const int wn = (wave & 1) * 64;

    const int r0 = tid >> 2;
    const int c0 = (tid & 3) * 8;
    const short* gA = A  + (size_t)(m0 + r0) * K + c0;
    const short* gB = Bt + (size_t)(n0 + r0) * K + c0;
    short* lA = As + wave * 512;
    short* lB = Bs + wave * 512;

    f32x4 acc[4][4];
#pragma unroll
    for (int i = 0; i < 4; ++i)
#pragma unroll
        for (int j = 0; j < 4; ++j) acc[i][j] = (f32x4){0.f, 0.f, 0.f, 0.f};

    for (int k0 = 0; k0 < K; k0 += 32) {
        __syncthreads();
        gl2lds16(gA + k0,                  lA);
        gl2lds16(gA + k0 + (size_t)64 * K, lA + 2048);
        gl2lds16(gB + k0,                  lB);
        gl2lds16(gB + k0 + (size_t)64 * K, lB + 2048);
        __syncthreads();

        bf16x8 av[4], bv[4];
#pragma unroll
        for (int mt = 0; mt < 4; ++mt)
            av[mt] = *(const bf16x8*)&As[(wm + mt * 16 + l16) * 32 + quad * 8];
#pragma unroll
        for (int nt = 0; nt < 4; ++nt)
            bv[nt] = *(const bf16x8*)&Bs[(wn + nt * 16 + l16) * 32 + quad * 8];
#pragma unroll
        for (int mt = 0; mt < 4; ++mt)
#pragma unroll
            for (int nt = 0; nt < 4; ++nt)
                acc[mt][nt] = __builtin_amdgcn_mfma_f32_16x16x32_bf16(
                    av[mt], bv[nt], acc[mt][nt], 0, 0, 0);
    }

#pragma unroll
    for (int mt = 0; mt < 4; ++mt)
#pragma unroll
        for (int nt = 0; nt < 4; ++nt) {
            int col = n0 + wn + nt * 16 + l16;
            float b = bias ? bias[col] : 0.f;
#pragma unroll
            for (int r = 0; r < 4; ++r) {
                int row = m0 + wm + mt * 16 + quad * 4 + r;
                C[(size_t)row * N + col] = acc[mt][nt][r] + b;
            }
        }
}

// ---------------------------------------------------------------------------
// RoPE in-place on fp32 Q columns of qkv (row stride QKVN).
// ---------------------------------------------------------------------------
__global__ void rope_kernel(float* __restrict__ x,
                            const float* __restrict__ cosp,
                            const float* __restrict__ sinp)
{
    int idx = blockIdx.x * blockDim.x + threadIdx.x;   // SEQ*NH*64
    int d = idx & 63;
    int h = (idx >> 6) & (NH - 1);
    int s = idx >> 10;
    if (s >= SEQ) return;
    float* base = x + (size_t)s * QKVN + h * DH;
    float x0 = base[d], x1 = base[d + 64];
    float c0 = cosp[s * DH + d],  c1 = cosp[s * DH + d + 64];
    float s0 = sinp[s * DH + d],  s1 = sinp[s * DH + d + 64];
    base[d]      = x0 * c0 - x1 * s0;
    base[d + 64] = x1 * c1 + x0 * s1;
}

// ---------------------------------------------------------------------------
// RoPE K (fp32, row stride QKVN) -> bf16 row-major [s][kvh*128+d].
// ---------------------------------------------------------------------------
__global__ void ropebf_k(const float* __restrict__ kp,
                         const float* __restrict__ cosp,
                         const float* __restrict__ sinp,
                         short* __restrict__ kb)
{
    int idx = blockIdx.x * blockDim.x + threadIdx.x;   // SEQ*NKV*64
    int d   = idx & 63;
    int kvh = (idx >> 6) & (NKV - 1);
    int s   = idx >> 7;
    if (s >= SEQ) return;
    const float* base = kp + (size_t)s * QKVN + kvh * DH;
    float x0 = base[d], x1 = base[d + 64];
    float c0 = cosp[s * DH + d],  c1 = cosp[s * DH + d + 64];
    float s0 = sinp[s * DH + d],  s1 = sinp[s * DH + d + 64];
    short* ob = kb + (size_t)s * (NKV * DH) + kvh * DH;
    ob[d]      = f2bf(x0 * c0 - x1 * s0);
    ob[d + 64] = f2bf(x1 * c1 + x0 * s1);
}

// ---------------------------------------------------------------------------
// V (fp32, row stride QKVN) -> bf16 transposed vt[kvh][d][s]
// ---------------------------------------------------------------------------
__global__ void vt_conv(const float* __restrict__ vp, short* __restrict__ vt)
{
    int idx = blockIdx.x * blockDim.x + threadIdx.x;   // NKV*128*SEQ
    int s   = idx & (SEQ - 1);
    int d   = (idx >> 11) & (DH - 1);
    int kvh = idx >> 18;
    vt[idx] = f2bf(vp[(size_t)s * QKVN + kvh * DH + d]);
}

// ---------------------------------------------------------------------------
// MFMA flash attention, transposed-score formulation.
// S^T = mfma(K_frag, Q_frag): per-lane column softmax (2+2 shuffles).
// O^T = mfma(V^T_frag, P_frag): alpha/l scaling per-lane, no broadcasts.
// 2 barriers/iter (P round-trip is wave-private). Heavy q-blocks first.
// ---------------------------------------------------------------------------
__global__ __launch_bounds__(256) void attn_mfma(const float* __restrict__ Qp,
                                                 const short* __restrict__ Kb,
                                                 const short* __restrict__ Vtb,
                                                 short* __restrict__ ctx)
{
    __shared__ short Ks[32][136];
    __shared__ short Vs[128][40];
    __shared__ short Ps[4][16][40];    // per-wave [q][k] A/B-operand layout

    const int bid = blockIdx.x;
    const int h   = bid & 15;
    const int qb  = 31 - (bid >> 4);   // heavy blocks dispatch first
    const int kvh = h >> 3;
    const int tid  = threadIdx.x;
    const int wave = tid >> 6;
    const int lane = tid & 63;
    const int quad = lane >> 4;
    const int l16  = lane & 15;

    const int qrow0 = qb * 64 + wave * 16;
    const int qg    = qrow0 + l16;       // this lane's q column

    // Q fragment: B-operand layout (n=l16 -> q-row, k=quad*8+j -> d)
    bf16x8 aq[4];
    {
        const float* qsrc = Qp + (size_t)(qrow0 + l16) * QKVN + h * DH + quad * 8;
#pragma unroll
        for (int c = 0; c < 4; ++c) {
            float4 f0 = *(const float4*)(qsrc + c * 32);
            float4 f1 = *(const float4*)(qsrc + c * 32 + 4);
            bf16x8 a;
            a[0] = f2bf(f0.x); a[1] = f2bf(f0.y); a[2] = f2bf(f0.z); a[3] = f2bf(f0.w);
            a[4] = f2bf(f1.x); a[5] = f2bf(f1.y); a[6] = f2bf(f1.z); a[7] = f2bf(f1.w);
            aq[c] = a;
        }
    }

    // O^T accumulator: of[t] row=d (t*16+quad*4+r), col=q (l16)
    f32x4 of[8];
#pragma unroll
    for (int t = 0; t < 8; ++t) of[t] = (f32x4){0.f, 0.f, 0.f, 0.f};
    float m_old = -1e30f, l_sum = 0.f;

    const int nkt = (qb + 1) * 2;
    const float SL = SCALE * LOG2E;

    for (int kt = 0; kt < nkt; ++kt) {
        const int kbase = kt * 32;
        __syncthreads();
        {   // stage K tile: 32x128 bf16 = 512 int4 chunks, 2/thread
#pragma unroll
            for (int i = 0; i < 2; ++i) {
                int cid = tid + i * 256;
                int r = cid >> 4, c = (cid & 15) * 8;
                *(int4*)&Ks[r][c] =
                    *(const int4*)(Kb + (size_t)(kbase + r) * (NKV * DH) + kvh * DH + c);
            }
        }
        {   // stage V^T tile: 128x32 bf16 = 512 int4 chunks, 2/thread
#pragma unroll
            for (int i = 0; i < 2; ++i) {
                int cid = tid + i * 256;
                int d = cid >> 2, c = (cid & 3) * 8;
                *(int4*)&Vs[d][c] =
                    *(const int4*)(Vtb + (size_t)kvh * DH * SEQ + (size_t)d * SEQ + kbase + c);
            }
        }
        __syncthreads();

        if (kbase > qrow0 + 15) continue;   // wave-uniform: fully masked tile

        // ---- S^T: D[k=quad*4+r][q=l16] = K·Q^T ----
        f32x4 s0 = (f32x4){0.f, 0.f, 0.f, 0.f};
        f32x4 s1 = (f32x4){0.f, 0.f, 0.f, 0.f};
#pragma unroll
        for (int c = 0; c < 4; ++c) {
            bf16x8 ak0 = *(const bf16x8*)&Ks[l16][c * 32 + quad * 8];
            bf16x8 ak1 = *(const bf16x8*)&Ks[16 + l16][c * 32 + quad * 8];
            s0 = __builtin_amdgcn_mfma_f32_16x16x32_bf16(ak0, aq[c], s0, 0, 0, 0);
            s1 = __builtin_amdgcn_mfma_f32_16x16x32_bf16(ak1, aq[c], s1, 0, 0, 0);
        }

        // ---- per-lane-column online softmax (log2 domain) ----
        float x[8];
#pragma unroll
        for (int r = 0; r < 4; ++r) {
            x[r]     = (kbase + quad * 4 + r      <= qg) ? s0[r] * SL : -1e30f;
            x[4 + r] = (kbase + 16 + quad * 4 + r <= qg) ? s1[r] * SL : -1e30f;
        }
        float mr = x[0];
#pragma unroll
        for (int i = 1; i < 8; ++i) mr = fmaxf(mr, x[i]);
        mr = fmaxf(mr, __shfl_xor(mr, 16));
        mr = fmaxf(mr, __shfl_xor(mr, 32));
        float mn    = fmaxf(m_old, mr);
        float alpha = __builtin_amdgcn_exp2f(m_old - mn);
        float p[8], ps = 0.f;
#pragma unroll
        for (int i = 0; i < 8; ++i) { p[i] = __builtin_amdgcn_exp2f(x[i] - mn); ps += p[i]; }
        ps += __shfl_xor(ps, 16);
        ps += __shfl_xor(ps, 32);
        l_sum = l_sum * alpha + ps;
        m_old = mn;

        // P^T (C-layout) -> Ps[wave][q=l16][k] (A/B-operand layout), 2x b64
        bf16x4 w0 = { f2bf(p[0]), f2bf(p[1]), f2bf(p[2]), f2bf(p[3]) };
        bf16x4 w1 = { f2bf(p[4]), f2bf(p[5]), f2bf(p[6]), f2bf(p[7]) };
        *(bf16x4*)&Ps[wave][l16][quad * 4]      = w0;
        *(bf16x4*)&Ps[wave][l16][16 + quad * 4] = w1;

        // rescale O^T by per-lane alpha
#pragma unroll
        for (int t = 0; t < 8; ++t)
#pragma unroll
            for (int r = 0; r < 4; ++r) of[t][r] *= alpha;

        // ---- O^T += V^T @ P: A=V^T (m=d), B=P (n=q) ----  (wave-private Ps)
        bf16x8 bp = *(const bf16x8*)&Ps[wave][l16][quad * 8];
#pragma unroll
        for (int t = 0; t < 8; ++t) {
            bf16x8 av = *(const bf16x8*)&Vs[t * 16 + l16][quad * 8];
            of[t] = __builtin_amdgcn_mfma_f32_16x16x32_bf16(av, bp, of[t], 0, 0, 0);
        }
    }

    // epilogue: O^T col=q (this lane), row d = t*16+quad*4+r; 8x 8B stores
    float inv = 1.f / l_sum;
    short* dst = ctx + (size_t)qg * HID + h * DH + quad * 4;
#pragma unroll
    for (int t = 0; t < 8; ++t) {
        bf16x4 wv = { f2bf(of[t][0] * inv), f2bf(of[t][1] * inv),
                      f2bf(of[t][2] * inv), f2bf(of[t][3] * inv) };
        *(bf16x4*)(dst + t * 16) = wv;
    }
}

// ---------------------------------------------------------------------------
extern "C" void kernel_launch(void* const* d_in, const int* in_sizes, int n_in,
                              void* d_out, int out_size, void* d_ws, size_t ws_size,
                              hipStream_t stream)
{
    const float* hs   = (const float*)d_in[0];
    const float* cosp = (const float*)d_in[1];
    const float* sinp = (const float*)d_in[2];
    const float* Wq = (const float*)d_in[4];
    const float* bq = (const float*)d_in[5];
    const float* Wk = (const float*)d_in[6];
    const float* bk = (const float*)d_in[7];
    const float* Wv = (const float*)d_in[8];
    const float* bv = (const float*)d_in[9];
    const float* Wo = (const float*)d_in[10];
    float* out = (float*)d_out;

    char* w = (char*)d_ws;
    short* hsb    = (short*)w;  w += (size_t)SEQ * HID * 2;
    short* btq    = (short*)w;  w += (size_t)QKVN * HID * 2;
    short* wot    = (short*)w;  w += (size_t)HID * HID * 2;
    float* biaskv = (float*)w;  w += QKVN * 4;
    float* qkv    = (float*)w;  w += (size_t)SEQ * QKVN * 4;
    short* kbf    = (short*)w;  w += (size_t)SEQ * (NKV * DH) * 2;
    short* vtb    = (short*)w;  w += (size_t)NKV * DH * SEQ * 2;
    short* ctxb   = (short*)w;

    cvt_bf16<<<(SEQ * HID) / 1024, 256, 0, stream>>>(hs, hsb);

    transp_bf<<<dim3(HID / 32, HID / 32), dim3(32, 8), 0, stream>>>(Wq, btq, HID, HID);
    transp_bf<<<dim3((NKV * DH) / 32, HID / 32), dim3(32, 8), 0, stream>>>(Wk, btq + (size_t)2048 * HID, NKV * DH, HID);
    transp_bf<<<dim3((NKV * DH) / 32, HID / 32), dim3(32, 8), 0, stream>>>(Wv, btq + (size_t)2304 * HID, NKV * DH, HID);
    transp_bf<<<dim3(HID / 32, HID / 32), dim3(32, 8), 0, stream>>>(Wo, wot, HID, HID);

    hipMemcpyAsync(biaskv,        bq, 2048 * 4, hipMemcpyDeviceToDevice, stream);
    hipMemcpyAsync(biaskv + 2048, bk,  256 * 4, hipMemcpyDeviceToDevice, stream);
    hipMemcpyAsync(biaskv + 2304, bv,  256 * 4, hipMemcpyDeviceToDevice, stream);

    gemm_bt<<<dim3(QKVN / 128, SEQ / 128), 256, 0, stream>>>(hsb, btq, biaskv, qkv, SEQ, QKVN, HID);

    rope_kernel<<<(SEQ * NH * 64) / 256, 256, 0, stream>>>(qkv, cosp, sinp);
    ropebf_k<<<(SEQ * NKV * 64) / 256, 256, 0, stream>>>(qkv + NH * DH, cosp, sinp, kbf);
    vt_conv<<<(NKV * DH * SEQ) / 256, 256, 0, stream>>>(qkv + NH * DH + NKV * DH, vtb);

    attn_mfma<<<dim3(32 * NH), 256, 0, stream>>>(qkv, kbf, vtb, ctxb);

    gemm_bt<<<dim3(HID / 128, SEQ / 128), 256, 0, stream>>>(ctxb, wot, nullptr, out, SEQ, HID, HID);
}